// Round 2
// baseline (496.004 us; speedup 1.0000x reference)
//
#include <hip/hip_runtime.h>
#include <hip/hip_bf16.h>

#define H 224
#define W 224
#define C 256
#define F 256
#define OB 14

typedef __attribute__((ext_vector_type(8))) short short8;
typedef __attribute__((ext_vector_type(4))) float f32x4;

__device__ __forceinline__ unsigned short f2bf(float f) {
    union { float f; unsigned u; } v; v.f = f;
    unsigned r = v.u + 0x7fffu + ((v.u >> 16) & 1u);
    return (unsigned short)(r >> 16);
}

// ---------------------------------------------------------------------------
// Weight repack: kernel[ky][kx][c][f] fp32  ->  bf16 B-fragment-major layout
// wrep[((kt*16 + nt)*64 + lane)*8 + j] = bf16(w[kk][c32*32 + quad*8 + j][nt*16 + lq])
// ---------------------------------------------------------------------------
__global__ __launch_bounds__(256) void repack_kernel(const float* __restrict__ wsrc,
                                                     unsigned short* __restrict__ wrep) {
    int g = blockIdx.x * 256 + threadIdx.x;   // < 72*16*64 = 73728
    int lane = g & 63;
    int nt   = (g >> 6) & 15;
    int kt   = g >> 10;
    int kk   = kt >> 3, c32 = kt & 7;
    int quad = lane >> 4, lq = lane & 15;
    int cbase = c32 * 32 + quad * 8;
    int f = nt * 16 + lq;
    alignas(16) unsigned short tmp[8];
#pragma unroll
    for (int j = 0; j < 8; ++j) {
        tmp[j] = f2bf(wsrc[((size_t)(kk * 256 + cbase + j)) * 256 + f]);
    }
    *reinterpret_cast<uint4*>(wrep + (size_t)g * 8) = *reinterpret_cast<const uint4*>(tmp);
}

__global__ void init_kernel(int* __restrict__ cnt) {
    cnt[0] = 0;
    cnt[1] = 0;
}

// ---------------------------------------------------------------------------
// Flags + compaction: active block ids packed to front of list, inactive to back.
// ---------------------------------------------------------------------------
__global__ __launch_bounds__(256) void flags_kernel(const float* __restrict__ mask,
                                                    int* __restrict__ list,
                                                    int* __restrict__ cnt) {
    int b = blockIdx.x;                 // (n, by, bx)
    int n = b >> 8, by = (b >> 4) & 15, bx = b & 15;
    int t = threadIdx.x;
    int r = t >> 4, s = t & 15;
    int gy = by * OB - 1 + r, gx = bx * OB - 1 + s;
    float v = 0.f;
    if ((unsigned)gy < (unsigned)H && (unsigned)gx < (unsigned)W)
        v = mask[((size_t)n * H + gy) * W + gx];
    __shared__ float red[256];
    red[t] = v;
    __syncthreads();
    if (t < 64) {
        float x = red[t] + red[t + 64] + red[t + 128] + red[t + 192];
#pragma unroll
        for (int off = 32; off; off >>= 1) x += __shfl_down(x, off);
        if (t == 0) {
            if (x > 0.5f * 256.0f) {
                int p = atomicAdd(&cnt[0], 1);
                list[p] = b;
            } else {
                int p = atomicAdd(&cnt[1], 1);
                list[1023 - p] = b;
            }
        }
    }
}

// ---------------------------------------------------------------------------
// Conv v3: ILP-pipelined, M_eff=14.
//   Round-1 post-mortem: pipes didn't overlap (serial sum of MFMA 64.5K +
//   LDS 41K + L2-B 40K + HBM 34K cyc/CU/block ~= measured ~190K). Fixes:
//   - 8 waves (512 thr), each wave: ALL 14 output rows x 32 f (acc[14][2]).
//     M_eff 7->14 halves B-fragment L2 traffic (1.15 MB/block).
//   - B register double-buffer (bA/bB): next group's 6 frags issued right
//     after current group's MFMAs -> L2 latency under ~1400cyc MFMA issue.
//   - Staging split stA/stB (4 float4 each), issued/written mid-chunk so
//     every vmem wait that could drain them is >= 2 MFMA half-groups away.
//   - Raw barrier (lgkmcnt(0) + s_barrier), NOT __syncthreads(): keeps
//     staging vmem in flight across the per-chunk barrier (T4).
//   - Rolling-row schedule: 16 ds_read per half-group feed 84 MFMAs.
//   Occupancy drops to 2 waves/SIMD by design; ILP replaces TLP (m97 lesson).
// ---------------------------------------------------------------------------
#define LOADB(BUF, C32IDX, KXIDX)                                               \
    do {                                                                        \
        const unsigned short* bp_ = wb + (size_t)(C32IDX) * 8192 +              \
                                    (size_t)(KXIDX) * 65536;                    \
        _Pragma("unroll")                                                       \
        for (int ky_ = 0; ky_ < 3; ++ky_) {                                     \
            BUF[ky_][0] = *reinterpret_cast<const short8*>(bp_ + ky_ * 196608); \
            BUF[ky_][1] = *reinterpret_cast<const short8*>(bp_ + ky_ * 196608 + 512); \
        }                                                                       \
    } while (0)

#define HALF_MFMA(BUF, GQBASE)                                                  \
    do {                                                                        \
        const unsigned short* ap_ = pc + acol + ((((GQBASE) + quad) ^ sw) << 3);\
        __builtin_amdgcn_s_setprio(1);                                          \
        _Pragma("unroll")                                                       \
        for (int rowl_ = 0; rowl_ < 16; ++rowl_) {                              \
            short8 a_ = *reinterpret_cast<const short8*>(ap_ + (rowl_ << 10));  \
            _Pragma("unroll")                                                   \
            for (int ky_ = 0; ky_ < 3; ++ky_) {                                 \
                const int r_ = rowl_ - ky_;                                     \
                if (r_ >= 0 && r_ < 14) {                                       \
                    acc[r_][0] = __builtin_amdgcn_mfma_f32_16x16x32_bf16(a_, BUF[ky_][0], acc[r_][0], 0, 0, 0); \
                    acc[r_][1] = __builtin_amdgcn_mfma_f32_16x16x32_bf16(a_, BUF[ky_][1], acc[r_][1], 0, 0, 0); \
                }                                                               \
            }                                                                   \
        }                                                                       \
        __builtin_amdgcn_s_setprio(0);                                          \
    } while (0)

__global__ __launch_bounds__(512, 2) void conv_kernel(const float* __restrict__ in,
                                                      const unsigned short* __restrict__ wrep,
                                                      const float* __restrict__ bias,
                                                      const int* __restrict__ list,
                                                      const int* __restrict__ cnt,
                                                      float* __restrict__ out) {
    __shared__ __align__(16) unsigned short patch[2][256 * 64];  // 2 x 32 KB

    const int bid = blockIdx.x;
    const int n_active = cnt[0];
    const int b = list[bid];
    const int n = b >> 8, by = (b >> 4) & 15, bx = b & 15;
    const int tid = threadIdx.x;
    const int gy0 = by * OB - 1, gx0 = bx * OB - 1;
    float* outB = out + (size_t)n * H * W * F;

    if (bid >= n_active) {
#pragma unroll 4
        for (int idx = tid; idx < 196 * 64; idx += 512) {
            int pix = idx >> 6, fv = idx & 63;
            int oy = pix / 14, ox = pix - oy * 14;
            size_t o = ((size_t)((by * OB + oy) * W + bx * OB + ox)) * F + fv * 4;
            *reinterpret_cast<float4*>(outB + o) = make_float4(0.f, 0.f, 0.f, 0.f);
        }
        return;
    }

    const int wave = tid >> 6, lane = tid & 63;
    const int quad = lane >> 4, lq = lane & 15;
    const int wn = wave;                       // 0..7 : f-tiles nt = wn*2, wn*2+1

    const float* inB = in + (size_t)n * H * W * C;

    // Staging geometry: thread stages unit chv (4ch) of pixels p0+32*it, it=0..7.
    // gx and (pix&15), (pix&7) are it-invariant -> single so base, stride 2048.
    const int chv = tid & 15;
    const int p0  = tid >> 4;                  // 0..31
    const int sgx = gx0 + (p0 & 15);
    const int sr0 = p0 >> 4;                   // 0..1 ; row = sr0 + 2*it
    const bool okx = (unsigned)sgx < (unsigned)W;
    const int so0 = (p0 << 6) + (((chv >> 1) ^ (p0 & 7)) << 3) + ((chv & 1) << 2);

    f32x4 acc[14][2];
#pragma unroll
    for (int r = 0; r < 14; ++r) { acc[r][0] = (f32x4)(0.f); acc[r][1] = (f32x4)(0.f); }

    const int scol_base = (lq > 13) ? 13 : lq;   // clamp garbage M lanes
    const unsigned short* wb = wrep + ((size_t)(wn * 2) * 64 + lane) * 8;

    short8 bA[3][2], bB[3][2];

    // ---- prologue: stage chunk 0; prefetch B for (cc=0, kx=0) both halves
#pragma unroll
    for (int it = 0; it < 8; ++it) {
        int gy = gy0 + sr0 + 2 * it;
        float4 v = make_float4(0.f, 0.f, 0.f, 0.f);
        if (okx && (unsigned)gy < (unsigned)H)
            v = *reinterpret_cast<const float4*>(inB + ((size_t)gy * W + sgx) * C + chv * 4);
        uint2 bb;
        bb.x = (unsigned)f2bf(v.x) | ((unsigned)f2bf(v.y) << 16);
        bb.y = (unsigned)f2bf(v.z) | ((unsigned)f2bf(v.w) << 16);
        *reinterpret_cast<uint2*>(&patch[0][so0 + it * 2048]) = bb;
    }
    LOADB(bA, 0, 0);
    LOADB(bB, 1, 0);
    asm volatile("s_waitcnt lgkmcnt(0)" ::: "memory");
    __builtin_amdgcn_s_barrier();

    int cur = 0;
    float4 stA[4], stB[4];
#pragma unroll 1
    for (int cc = 0; cc < 4; ++cc) {
        const int pf = (cc < 3);
        const unsigned short* pc = &patch[0][0] + cur * (256 * 64);
#pragma unroll 1
        for (int kx3 = 0; kx3 < 3; ++kx3) {
            const int scol = scol_base + kx3;    // <= 15
            const int sw = scol & 7;
            const int acol = scol << 6;

            // ---- half A (c32l = 0): consume bA, then refill it
            HALF_MFMA(bA, 0);
            if (kx3 < 2)      LOADB(bA, cc * 2, kx3 + 1);
            else if (pf)      LOADB(bA, (cc + 1) * 2, 0);

            if (kx3 == 0 && pf) {
                // issue first half of next-chunk staging (drain >= 2 half-groups away)
#pragma unroll
                for (int it = 0; it < 4; ++it) {
                    int gy = gy0 + sr0 + 2 * it;
                    stA[it] = make_float4(0.f, 0.f, 0.f, 0.f);
                    if (okx && (unsigned)gy < (unsigned)H)
                        stA[it] = *reinterpret_cast<const float4*>(
                            inB + ((size_t)gy * W + sgx) * C + (cc + 1) * 64 + chv * 4);
                }
            }
            if (kx3 == 1 && pf) {
                // write first half into idle LDS buffer; issue second half
#pragma unroll
                for (int it = 0; it < 4; ++it) {
                    uint2 bb;
                    bb.x = (unsigned)f2bf(stA[it].x) | ((unsigned)f2bf(stA[it].y) << 16);
                    bb.y = (unsigned)f2bf(stA[it].z) | ((unsigned)f2bf(stA[it].w) << 16);
                    *reinterpret_cast<uint2*>(&patch[cur ^ 1][so0 + it * 2048]) = bb;
                }
#pragma unroll
                for (int it = 4; it < 8; ++it) {
                    int gy = gy0 + sr0 + 2 * it;
                    stB[it - 4] = make_float4(0.f, 0.f, 0.f, 0.f);
                    if (okx && (unsigned)gy < (unsigned)H)
                        stB[it - 4] = *reinterpret_cast<const float4*>(
                            inB + ((size_t)gy * W + sgx) * C + (cc + 1) * 64 + chv * 4);
                }
            }
            if (kx3 == 2 && pf) {
#pragma unroll
                for (int it = 4; it < 8; ++it) {
                    uint2 bb;
                    bb.x = (unsigned)f2bf(stB[it - 4].x) | ((unsigned)f2bf(stB[it - 4].y) << 16);
                    bb.y = (unsigned)f2bf(stB[it - 4].z) | ((unsigned)f2bf(stB[it - 4].w) << 16);
                    *reinterpret_cast<uint2*>(&patch[cur ^ 1][so0 + it * 2048]) = bb;
                }
            }

            // ---- half B (c32l = 1): consume bB, then refill it
            HALF_MFMA(bB, 4);
            if (kx3 < 2)      LOADB(bB, cc * 2 + 1, kx3 + 1);
            else if (pf)      LOADB(bB, (cc + 1) * 2 + 1, 0);
        }
        if (pf) {
            asm volatile("s_waitcnt lgkmcnt(0)" ::: "memory");
            __builtin_amdgcn_s_barrier();
            cur ^= 1;
        }
    }

    // Epilogue. D layout: M-index (output col ox) = quad*4 + reg, N-index = lq.
    const float bv0 = bias[wn * 32 + lq];
    const float bv1 = bias[wn * 32 + 16 + lq];
#pragma unroll
    for (int r = 0; r < 14; ++r) {
#pragma unroll
        for (int j = 0; j < 4; ++j) {
            const int ox = quad * 4 + j;
            if (ox < 14) {
                size_t o = ((size_t)((by * OB + r) * W + bx * OB + ox)) * F + wn * 32 + lq;
                float v0 = acc[r][0][j] + bv0;
                float v1 = acc[r][1][j] + bv1;
                outB[o]      = v0 > 0.f ? v0 : 0.f;
                outB[o + 16] = v1 > 0.f ? v1 : 0.f;
            }
        }
    }
}

extern "C" void kernel_launch(void* const* d_in, const int* in_sizes, int n_in,
                              void* d_out, int out_size, void* d_ws, size_t ws_size,
                              hipStream_t stream) {
    const float* inputs = (const float*)d_in[0];
    const float* mask   = (const float*)d_in[1];
    const float* wsrc   = (const float*)d_in[2];
    const float* bias   = (const float*)d_in[3];
    float* outp = (float*)d_out;

    unsigned short* wrep = (unsigned short*)d_ws;              // 1,179,648 B
    int* list = (int*)((char*)d_ws + 1179648);                 // 1024 ints
    int* cnt  = (int*)((char*)d_ws + 1179648 + 4096);          // 2 ints

    hipLaunchKernelGGL(init_kernel, dim3(1), dim3(1), 0, stream, cnt);
    hipLaunchKernelGGL(repack_kernel, dim3(288), dim3(256), 0, stream, wsrc, wrep);
    hipLaunchKernelGGL(flags_kernel, dim3(1024), dim3(256), 0, stream, mask, list, cnt);
    hipLaunchKernelGGL(conv_kernel, dim3(1024), dim3(512), 0, stream,
                       inputs, wrep, bias, list, cnt, outp);
}

// Round 3
// 465.176 us; speedup vs baseline: 1.0663x; 1.0663x over previous
//
#include <hip/hip_runtime.h>
#include <hip/hip_bf16.h>

#define H 224
#define W 224
#define C 256
#define F 256
#define OB 14

typedef __attribute__((ext_vector_type(8))) short short8;
typedef __attribute__((ext_vector_type(4))) float f32x4;

__device__ __forceinline__ unsigned short f2bf(float f) {
    union { float f; unsigned u; } v; v.f = f;
    unsigned r = v.u + 0x7fffu + ((v.u >> 16) & 1u);
    return (unsigned short)(r >> 16);
}

// ---------------------------------------------------------------------------
// Weight repack: kernel[ky][kx][c][f] fp32  ->  bf16 B-fragment-major layout
// wrep[((kt*16 + nt)*64 + lane)*8 + j] = bf16(w[kk][c32*32 + quad*8 + j][nt*16 + lq])
// ---------------------------------------------------------------------------
__global__ __launch_bounds__(256) void repack_kernel(const float* __restrict__ wsrc,
                                                     unsigned short* __restrict__ wrep) {
    int g = blockIdx.x * 256 + threadIdx.x;   // < 72*16*64 = 73728
    int lane = g & 63;
    int nt   = (g >> 6) & 15;
    int kt   = g >> 10;
    int kk   = kt >> 3, c32 = kt & 7;
    int quad = lane >> 4, lq = lane & 15;
    int cbase = c32 * 32 + quad * 8;
    int f = nt * 16 + lq;
    alignas(16) unsigned short tmp[8];
#pragma unroll
    for (int j = 0; j < 8; ++j) {
        tmp[j] = f2bf(wsrc[((size_t)(kk * 256 + cbase + j)) * 256 + f]);
    }
    *reinterpret_cast<uint4*>(wrep + (size_t)g * 8) = *reinterpret_cast<const uint4*>(tmp);
}

// ---------------------------------------------------------------------------
// Conv v4 = r1-winner structure (best measured: 165us conv) + two safe changes:
//  (a) active-test fused into conv prologue (kills init+flags launches; the
//      16x16 mask reduce overlaps chunk-0 staging).
//  (b) raw lgkmcnt(0)+s_barrier instead of __syncthreads (no vmcnt(0) drain).
// r2 lesson (hard constraint): 1024-thr block => 4 waves/SIMD resident =>
//  <=128 unified regs/wave. r1's 64 VGPR + 56 AGPR = 120 is already at the
//  ceiling; no room for B double-buffering at this block shape. Do NOT add
//  register arrays here.
// ---------------------------------------------------------------------------
__global__ __launch_bounds__(1024, 4) void conv_kernel(const float* __restrict__ in,
                                                       const unsigned short* __restrict__ wrep,
                                                       const float* __restrict__ bias,
                                                       const float* __restrict__ mask,
                                                       float* __restrict__ out) {
    __shared__ __align__(16) unsigned short patch[2][256 * 64];  // 2 x 32 KB
    __shared__ float red[256];
    __shared__ int s_active;

    const int b = blockIdx.x;
    const int n = b >> 8, by = (b >> 4) & 15, bx = b & 15;
    const int tid = threadIdx.x;
    const int gy0 = by * OB - 1, gx0 = bx * OB - 1;
    float* outB = out + (size_t)n * H * W * F;

    const int wave = tid >> 6, lane = tid & 63;
    const int quad = lane >> 4, lq = lane & 15;
    const int wm = wave >> 3;          // 0..1 : rows wm*7 .. wm*7+6
    const int wn = wave & 7;           // 0..7 : f-tiles nt = wn*2, wn*2+1

    const float* inB = in + (size_t)n * H * W * C;

    // Staging geometry (r1): thread stages 4 uint2 units (4ch each) per chunk.
    const float* sp[4];
    int so[4];
#pragma unroll
    for (int it = 0; it < 4; ++it) {
        int idx = tid + (it << 10);          // 0..4095
        int pix = idx >> 4, chv = idx & 15;  // pixel 0..255, 4-ch unit 0..15
        int rr = pix >> 4, ss = pix & 15;
        int gy = gy0 + rr, gx = gx0 + ss;
        bool ok = ((unsigned)gy < (unsigned)H) && ((unsigned)gx < (unsigned)W);
        sp[it] = ok ? (inB + ((size_t)(gy * W + gx)) * C + chv * 4) : nullptr;
        so[it] = (pix << 6) + (((chv >> 1) ^ (pix & 7)) << 3) + ((chv & 1) << 2);
    }

    // ---- fused active-test: load 16x16 mask tile (threads 0..255)
    if (tid < 256) {
        int rr = tid >> 4, ss = tid & 15;
        int gy = gy0 + rr, gx = gx0 + ss;
        float mv = 0.f;
        if ((unsigned)gy < (unsigned)H && (unsigned)gx < (unsigned)W)
            mv = mask[((size_t)n * H + gy) * W + gx];
        red[tid] = mv;
    }

    // ---- prologue: stage chunk 0 into patch[0] (overlaps mask loads)
#pragma unroll
    for (int it = 0; it < 4; ++it) {
        float4 v = make_float4(0.f, 0.f, 0.f, 0.f);
        if (sp[it]) v = *reinterpret_cast<const float4*>(sp[it]);
        uint2 bb;
        bb.x = (unsigned)f2bf(v.x) | ((unsigned)f2bf(v.y) << 16);
        bb.y = (unsigned)f2bf(v.z) | ((unsigned)f2bf(v.w) << 16);
        *reinterpret_cast<uint2*>(&patch[0][so[it]]) = bb;
    }
    asm volatile("s_waitcnt lgkmcnt(0)" ::: "memory");
    __builtin_amdgcn_s_barrier();

    if (tid < 64) {
        float x = red[tid] + red[tid + 64] + red[tid + 128] + red[tid + 192];
#pragma unroll
        for (int off = 32; off; off >>= 1) x += __shfl_down(x, off);
        if (tid == 0) s_active = (x > 128.0f) ? 1 : 0;
    }
    asm volatile("s_waitcnt lgkmcnt(0)" ::: "memory");
    __builtin_amdgcn_s_barrier();

    if (!s_active) {
#pragma unroll 4
        for (int idx = tid; idx < 196 * 64; idx += 1024) {
            int pix = idx >> 6, fv = idx & 63;
            int oy = pix / 14, ox = pix - oy * 14;
            size_t o = ((size_t)((by * OB + oy) * W + bx * OB + ox)) * F + fv * 4;
            *reinterpret_cast<float4*>(outB + o) = make_float4(0.f, 0.f, 0.f, 0.f);
        }
        return;
    }

    f32x4 acc[7][2];
#pragma unroll
    for (int r = 0; r < 7; ++r) { acc[r][0] = (f32x4)(0.f); acc[r][1] = (f32x4)(0.f); }

    const int scol_base = (lq > 13) ? 13 : lq;   // clamp garbage M lanes
    const unsigned short* wb = wrep + ((size_t)(wn * 2) * 64 + lane) * 8;
    const int arow_base = (wm * 7 * 16) << 6;    // elem offset of wave's row-0

    int cur = 0;
    float4 st[4];
#pragma unroll 1
    for (int cc = 0; cc < 4; ++cc) {
        const int pf = (cc < 3);
        if (pf) {
            // issue next-chunk staging loads early; converted+written at kx==0
#pragma unroll
            for (int it = 0; it < 4; ++it) {
                st[it] = make_float4(0.f, 0.f, 0.f, 0.f);
                if (sp[it]) st[it] = *reinterpret_cast<const float4*>(sp[it] + (cc + 1) * 64);
            }
        }
        const unsigned short* pc = &patch[0][0] + cur * (256 * 64);
#pragma unroll 1
        for (int kx3 = 0; kx3 < 3; ++kx3) {
            const int scol = scol_base + kx3;    // <= 15
            const int sw = scol & 7;
            const int acol = arow_base + (scol << 6);
#pragma unroll 1
            for (int c32l = 0; c32l < 2; ++c32l) {
                const unsigned short* wbk = wb + (cc * 2 + c32l) * 8192 + kx3 * 65536;
                short8 bf[3][2];
#pragma unroll
                for (int ky = 0; ky < 3; ++ky) {
                    bf[ky][0] = *reinterpret_cast<const short8*>(wbk + ky * 196608);
                    bf[ky][1] = *reinterpret_cast<const short8*>(wbk + ky * 196608 + 512);
                }
                const unsigned short* ap = pc + acol + ((((c32l << 2) + quad) ^ sw) << 3);
                __builtin_amdgcn_s_setprio(1);
#pragma unroll
                for (int rowl = 0; rowl < 9; ++rowl) {
                    short8 a = *reinterpret_cast<const short8*>(ap + (rowl << 10));
#pragma unroll
                    for (int ky = 0; ky < 3; ++ky) {
                        const int r = rowl - ky;
                        if (r >= 0 && r < 7) {
                            acc[r][0] = __builtin_amdgcn_mfma_f32_16x16x32_bf16(a, bf[ky][0], acc[r][0], 0, 0, 0);
                            acc[r][1] = __builtin_amdgcn_mfma_f32_16x16x32_bf16(a, bf[ky][1], acc[r][1], 0, 0, 0);
                        }
                    }
                }
                __builtin_amdgcn_s_setprio(0);
            }
            if (kx3 == 0 && pf) {
                // convert + write next chunk into the idle LDS half
#pragma unroll
                for (int it = 0; it < 4; ++it) {
                    uint2 bb;
                    bb.x = (unsigned)f2bf(st[it].x) | ((unsigned)f2bf(st[it].y) << 16);
                    bb.y = (unsigned)f2bf(st[it].z) | ((unsigned)f2bf(st[it].w) << 16);
                    *reinterpret_cast<uint2*>(&patch[cur ^ 1][so[it]]) = bb;
                }
            }
        }
        if (pf) {
            asm volatile("s_waitcnt lgkmcnt(0)" ::: "memory");
            __builtin_amdgcn_s_barrier();
            cur ^= 1;
        }
    }

    // Epilogue. D layout: M-index (output col ox) = quad*4 + reg, N-index = lq.
    const float bv0 = bias[wn * 32 + lq];
    const float bv1 = bias[wn * 32 + 16 + lq];
#pragma unroll
    for (int r = 0; r < 7; ++r) {
        const int oy = wm * 7 + r;
#pragma unroll
        for (int j = 0; j < 4; ++j) {
            const int ox = quad * 4 + j;
            if (ox < 14) {
                size_t o = ((size_t)((by * OB + oy) * W + bx * OB + ox)) * F + wn * 32 + lq;
                float v0 = acc[r][0][j] + bv0;
                float v1 = acc[r][1][j] + bv1;
                outB[o]      = v0 > 0.f ? v0 : 0.f;
                outB[o + 16] = v1 > 0.f ? v1 : 0.f;
            }
        }
    }
}

extern "C" void kernel_launch(void* const* d_in, const int* in_sizes, int n_in,
                              void* d_out, int out_size, void* d_ws, size_t ws_size,
                              hipStream_t stream) {
    const float* inputs = (const float*)d_in[0];
    const float* mask   = (const float*)d_in[1];
    const float* wsrc   = (const float*)d_in[2];
    const float* bias   = (const float*)d_in[3];
    float* outp = (float*)d_out;

    unsigned short* wrep = (unsigned short*)d_ws;              // 1,179,648 B

    hipLaunchKernelGGL(repack_kernel, dim3(288), dim3(256), 0, stream, wsrc, wrep);
    hipLaunchKernelGGL(conv_kernel, dim3(1024), dim3(1024), 0, stream,
                       inputs, wrep, bias, mask, outp);
}